// Round 3
// baseline (437.135 us; speedup 1.0000x reference)
//
#include <hip/hip_runtime.h>
#include <math.h>

typedef __attribute__((ext_vector_type(8))) short bf16x8;
typedef __attribute__((ext_vector_type(4))) float f32x4;

#define NTOK 64
#define NWMASK 192

__device__ __forceinline__ unsigned short f2bf(float f) {
  union { float f; unsigned u; } v; v.f = f;
  return (unsigned short)((v.u + 0x7fffu + ((v.u >> 16) & 1u)) >> 16);
}

// ---------------- polar position bias (once, tiny) ----------------
__global__ void pb_kernel(const float* __restrict__ Wp1, const float* __restrict__ bp1,
                          const float* __restrict__ Wp2, const float* __restrict__ bp2,
                          float* __restrict__ pb) {
  int idx = blockIdx.x * 256 + threadIdx.x;     // (i,j) pair, 4096 total
  if (idx >= 4096) return;
  int i = idx >> 6, j = idx & 63;
  float dx = (float)((i & 7) - (j & 7));
  float dy = -(float)((i >> 3) - (j >> 3));
  float r = sqrtf(dx*dx + dy*dy + 1e-9f);
  float theta = atan2f(dx, dy);
  float p0 = r * (1.0f / 9.899494936611665f);
  float p1 = (theta + 3.14159265358979323846f) * (1.0f / 6.283185307179586f);
  float a0 = 0.f, a1 = 0.f, a2 = 0.f, a3 = 0.f;
  for (int f = 0; f < 64; ++f) {
    float hpre = p0 * Wp1[2*f] + p1 * Wp1[2*f+1] + bp1[f];
    float g = 0.5f * hpre * (1.0f + erff(hpre * 0.70710678118654752f));
    a0 += Wp2[f]       * g;
    a1 += Wp2[64 + f]  * g;
    a2 += Wp2[128 + f] * g;
    a3 += Wp2[192 + f] * g;
  }
  pb[idx]          = a0 + bp2[0];
  pb[4096 + idx]   = a1 + bp2[1];
  pb[8192 + idx]   = a2 + bp2[2];
  pb[12288 + idx]  = a3 + bp2[3];
}

// ---------------- K1: qkv + qk2 projection (bf16 MFMA) ----------------
// C[196608 x 640] = X[196608 x 128] @ W~^T ; W~ rows: [q|k|v](Wqkv) ++ [q2|k2](Wqkv2)
// out layout per (b, mat, h) 2048-elem block:
//   mats 0,1,3,4 (q,k,q2,k2): [tok(64)][d(32)]   (A/B-frag contiguous along d)
//   mat  2       (v)        : [d(32)][tok(64)]   (PV B-frag contiguous along tok)
// q/q2 pre-scaled by HD^-0.5
__global__ __launch_bounds__(256, 2)
void qkv_proj(const float* __restrict__ x,
              const float* __restrict__ Wqkv, const float* __restrict__ bqkv,
              const float* __restrict__ Wqkv2, const float* __restrict__ bqkv2,
              unsigned short* __restrict__ qkv) {
  __shared__ unsigned short Xl[128 * 128];   // [row][16B-unit ^ (row&7)]
  __shared__ unsigned short Wl[128 * 128];

  const int t = threadIdx.x;
  const int w = t >> 6;
  const int lane = t & 63;
  const int m = lane & 15;
  const int quad = lane >> 4;
  const int tau0 = blockIdx.x * 128;

  // stage X (fp32 -> bf16, XOR-swizzled 16B units)
#pragma unroll
  for (int u = 0; u < 8; ++u) {
    int id = u * 256 + t;
    int r = id >> 4, c16 = id & 15;
    const float* src = x + (size_t)(tau0 + r) * 128 + c16 * 8;
    float4 lo = *(const float4*)(src);
    float4 hi = *(const float4*)(src + 4);
    bf16x8 pk;
    pk[0] = (short)f2bf(lo.x); pk[1] = (short)f2bf(lo.y);
    pk[2] = (short)f2bf(lo.z); pk[3] = (short)f2bf(lo.w);
    pk[4] = (short)f2bf(hi.x); pk[5] = (short)f2bf(hi.y);
    pk[6] = (short)f2bf(hi.z); pk[7] = (short)f2bf(hi.w);
    *(bf16x8*)(&Xl[r * 128 + (c16 ^ (r & 7)) * 8]) = pk;
  }

  auto stageW = [&](int nblk) {
#pragma unroll
    for (int u = 0; u < 8; ++u) {
      int id = u * 256 + t;
      int r = id >> 4, c16 = id & 15;
      const float* src = (nblk < 3)
          ? (Wqkv + (size_t)(nblk * 128 + r) * 128 + c16 * 8)
          : (Wqkv2 + (size_t)((nblk - 3) * 128 + r) * 128 + c16 * 8);
      float4 lo = *(const float4*)(src);
      float4 hi = *(const float4*)(src + 4);
      bf16x8 pk;
      pk[0] = (short)f2bf(lo.x); pk[1] = (short)f2bf(lo.y);
      pk[2] = (short)f2bf(lo.z); pk[3] = (short)f2bf(lo.w);
      pk[4] = (short)f2bf(hi.x); pk[5] = (short)f2bf(hi.y);
      pk[6] = (short)f2bf(hi.z); pk[7] = (short)f2bf(hi.w);
      *(bf16x8*)(&Wl[r * 128 + (c16 ^ (r & 7)) * 8]) = pk;
    }
  };
  stageW(0);

  for (int nblk = 0; nblk < 5; ++nblk) {
    __syncthreads();   // staged X/W visible
    f32x4 acc[4][4];
#pragma unroll
    for (int mi = 0; mi < 4; ++mi)
#pragma unroll
      for (int ni = 0; ni < 4; ++ni) acc[mi][ni] = (f32x4){0.f, 0.f, 0.f, 0.f};

#pragma unroll
    for (int ks = 0; ks < 4; ++ks) {
      bf16x8 af[4], bfr[4];
      int unit = (ks * 4 + quad) ^ (m & 7);
#pragma unroll
      for (int mi = 0; mi < 4; ++mi) {
        int row = (w & 1) * 64 + mi * 16 + m;
        af[mi] = *(const bf16x8*)(&Xl[row * 128 + unit * 8]);
      }
#pragma unroll
      for (int ni = 0; ni < 4; ++ni) {
        int row = (w >> 1) * 64 + ni * 16 + m;
        bfr[ni] = *(const bf16x8*)(&Wl[row * 128 + unit * 8]);
      }
#pragma unroll
      for (int mi = 0; mi < 4; ++mi)
#pragma unroll
        for (int ni = 0; ni < 4; ++ni)
          acc[mi][ni] = __builtin_amdgcn_mfma_f32_16x16x32_bf16(
              af[mi], bfr[ni], acc[mi][ni], 0, 0, 0);
    }
    __syncthreads();   // all waves done reading Wl
    if (nblk < 4) stageW(nblk + 1);

    // epilogue
    const int bb = 2 * blockIdx.x + (w & 1);
    if (nblk == 2) {
      // V: transposed [d][tok], packed ushort4 stores (4 consecutive tokens)
#pragma unroll
      for (int ni = 0; ni < 4; ++ni) {
        int f7 = (w >> 1) * 64 + ni * 16 + m;       // 0..127 within mat
        float bias = bqkv[256 + f7];
        int hh = f7 >> 5, d = f7 & 31;
        size_t basev = ((size_t)(bb * 5 + 2) * 4 + hh) * 2048 + (size_t)d * 64;
#pragma unroll
        for (int mi = 0; mi < 4; ++mi) {
          int tok0 = mi * 16 + quad * 4;
          ushort4 pk;
          pk.x = f2bf(acc[mi][ni][0] + bias);
          pk.y = f2bf(acc[mi][ni][1] + bias);
          pk.z = f2bf(acc[mi][ni][2] + bias);
          pk.w = f2bf(acc[mi][ni][3] + bias);
          *(ushort4*)(qkv + basev + tok0) = pk;
        }
      }
    } else {
      const float scale = (nblk == 0 || nblk == 3) ? 0.17677669529663687f : 1.0f;
#pragma unroll
      for (int ni = 0; ni < 4; ++ni) {
        int f7 = (w >> 1) * 64 + ni * 16 + m;
        int fg = nblk * 128 + f7;
        float bias = (fg < 384) ? bqkv[fg] : bqkv2[fg - 384];
        int hh = f7 >> 5, d = f7 & 31;
        size_t baseq = ((size_t)(bb * 5 + nblk) * 4 + hh) * 2048 + d;
#pragma unroll
        for (int mi = 0; mi < 4; ++mi) {
          int tok0 = mi * 16 + quad * 4;
#pragma unroll
          for (int reg = 0; reg < 4; ++reg)
            qkv[baseq + (size_t)(tok0 + reg) * 32] =
                f2bf((acc[mi][ni][reg] + bias) * scale);
        }
      }
    }
  }
}

// ---------------- K2: attention core, one wave per head ----------------
__global__ __launch_bounds__(256, 4)
void attn_core(const unsigned short* __restrict__ qkv,
               const float* __restrict__ mask, const float* __restrict__ pb,
               const float* __restrict__ lq1, const float* __restrict__ lk1,
               const float* __restrict__ lq2, const float* __restrict__ lk2,
               const float* __restrict__ subln,
               unsigned short* __restrict__ obuf) {
  __shared__ unsigned short Pl[4][64 * 72];   // per-head P (bf16), pitch 72

  const int b = blockIdx.x;
  const int t = threadIdx.x;
  const int h = t >> 6;
  const int lane = t & 63;
  const int n15 = lane & 15, quad = lane >> 4;

  float lam;
  {
    float s1 = 0.f, s2 = 0.f;
#pragma unroll
    for (int i = 0; i < 16; ++i) { s1 += lq1[i] * lk1[i]; s2 += lq2[i] * lk2[i]; }
    lam = expf(s1) - expf(s2) + 0.2f;
  }

  const unsigned short* base = qkv + ((size_t)b * 5 * 4 + h) * 2048;
  // mats strided by 4*2048 = 8192 elems: 0=q 1=k 2=v(T) 3=q2 4=k2
  bf16x8 qf[4], kf[4], q2f[4], k2f[4];
#pragma unroll
  for (int i = 0; i < 4; ++i) {
    size_t off = (size_t)(i * 16 + n15) * 32 + quad * 8;
    qf[i]  = *(const bf16x8*)(base + 0 * 8192 + off);
    kf[i]  = *(const bf16x8*)(base + 1 * 8192 + off);
    q2f[i] = *(const bf16x8*)(base + 3 * 8192 + off);
    k2f[i] = *(const bf16x8*)(base + 4 * 8192 + off);
  }
  // V fragments from transposed layout [d][tok]: contiguous bf16x8
  const unsigned short* vsrc = base + 2 * 8192;
  bf16x8 vb[2][2];
#pragma unroll
  for (int nd = 0; nd < 2; ++nd)
#pragma unroll
    for (int kc = 0; kc < 2; ++kc)
      vb[nd][kc] = *(const bf16x8*)(vsrc + (size_t)(nd * 16 + n15) * 64 + kc * 32 + quad * 8);

  const float* pbh = pb + h * 4096;
  const float* mk = mask + (size_t)(b % NWMASK) * 4096;
  const f32x4 zero4 = (f32x4){0.f, 0.f, 0.f, 0.f};

  f32x4 S[4][4];
#pragma unroll
  for (int mi = 0; mi < 4; ++mi)
#pragma unroll
    for (int ni = 0; ni < 4; ++ni) {
      f32x4 c;
#pragma unroll
      for (int reg = 0; reg < 4; ++reg) {
        int row = mi * 16 + quad * 4 + reg, col = ni * 16 + n15;
        c[reg] = pbh[row * 64 + col] + mk[row * 64 + col];
      }
      f32x4 t2 = __builtin_amdgcn_mfma_f32_16x16x32_bf16(q2f[mi], k2f[ni], zero4, 0, 0, 0);
      f32x4 s = __builtin_amdgcn_mfma_f32_16x16x32_bf16(qf[mi], kf[ni], c, 0, 0, 0);
#pragma unroll
      for (int reg = 0; reg < 4; ++reg) s[reg] -= lam * t2[reg];
      S[mi][ni] = s;
    }

  // softmax: row = mi*16 + quad*4 + reg; 64 cols = 4 ni-tiles x 16 lanes
#pragma unroll
  for (int mi = 0; mi < 4; ++mi) {
#pragma unroll
    for (int reg = 0; reg < 4; ++reg) {
      float mx = fmaxf(fmaxf(S[mi][0][reg], S[mi][1][reg]),
                       fmaxf(S[mi][2][reg], S[mi][3][reg]));
      mx = fmaxf(mx, __shfl_xor(mx, 1));
      mx = fmaxf(mx, __shfl_xor(mx, 2));
      mx = fmaxf(mx, __shfl_xor(mx, 4));
      mx = fmaxf(mx, __shfl_xor(mx, 8));
      float e0 = __expf(S[mi][0][reg] - mx);
      float e1 = __expf(S[mi][1][reg] - mx);
      float e2 = __expf(S[mi][2][reg] - mx);
      float e3 = __expf(S[mi][3][reg] - mx);
      float sum = e0 + e1 + e2 + e3;
      sum += __shfl_xor(sum, 1);
      sum += __shfl_xor(sum, 2);
      sum += __shfl_xor(sum, 4);
      sum += __shfl_xor(sum, 8);
      float inv = 1.0f / sum;
      int row = mi * 16 + quad * 4 + reg;
      Pl[h][row * 72 +  0 + n15] = f2bf(e0 * inv);
      Pl[h][row * 72 + 16 + n15] = f2bf(e1 * inv);
      Pl[h][row * 72 + 32 + n15] = f2bf(e2 * inv);
      Pl[h][row * 72 + 48 + n15] = f2bf(e3 * inv);
    }
  }
  __syncthreads();

  f32x4 O[4][2];
#pragma unroll
  for (int mi = 0; mi < 4; ++mi) {
    O[mi][0] = zero4; O[mi][1] = zero4;
#pragma unroll
    for (int kc = 0; kc < 2; ++kc) {
      bf16x8 pa = *(const bf16x8*)(&Pl[h][(mi * 16 + n15) * 72 + kc * 32 + quad * 8]);
      O[mi][0] = __builtin_amdgcn_mfma_f32_16x16x32_bf16(pa, vb[0][kc], O[mi][0], 0, 0, 0);
      O[mi][1] = __builtin_amdgcn_mfma_f32_16x16x32_bf16(pa, vb[1][kc], O[mi][1], 0, 0, 0);
    }
  }

  // RMSNorm per row, scale, store bf16 to obuf[b][tok][h*32+d]
  float w0 = subln[n15] * 0.8f;
  float w1 = subln[16 + n15] * 0.8f;
#pragma unroll
  for (int mi = 0; mi < 4; ++mi) {
#pragma unroll
    for (int reg = 0; reg < 4; ++reg) {
      float a0 = O[mi][0][reg], a1 = O[mi][1][reg];
      float ss = a0 * a0 + a1 * a1;
      ss += __shfl_xor(ss, 1);
      ss += __shfl_xor(ss, 2);
      ss += __shfl_xor(ss, 4);
      ss += __shfl_xor(ss, 8);
      float rs = 1.0f / sqrtf(ss * (1.0f / 32.0f) + 1e-9f);
      int row = mi * 16 + quad * 4 + reg;
      size_t o0 = ((size_t)b * 64 + row) * 128 + h * 32;
      obuf[o0 + n15]      = f2bf(a0 * rs * w0);
      obuf[o0 + 16 + n15] = f2bf(a1 * rs * w1);
    }
  }
}

// ---------------- K3: output projection (bf16 MFMA, fp32 out) ----------------
__global__ __launch_bounds__(256, 2)
void out_proj(const unsigned short* __restrict__ obuf,
              const float* __restrict__ Wproj, const float* __restrict__ bproj,
              float* __restrict__ out) {
  __shared__ unsigned short Al[128 * 128];
  __shared__ unsigned short Wl[128 * 128];

  const int t = threadIdx.x;
  const int w = t >> 6;
  const int lane = t & 63;
  const int m = lane & 15;
  const int quad = lane >> 4;
  const int tau0 = blockIdx.x * 128;

#pragma unroll
  for (int u = 0; u < 8; ++u) {
    int id = u * 256 + t;
    int r = id >> 4, c16 = id & 15;
    bf16x8 v = *(const bf16x8*)(obuf + (size_t)(tau0 + r) * 128 + c16 * 8);
    *(bf16x8*)(&Al[r * 128 + (c16 ^ (r & 7)) * 8]) = v;
  }
#pragma unroll
  for (int u = 0; u < 8; ++u) {
    int id = u * 256 + t;
    int r = id >> 4, c16 = id & 15;
    const float* src = Wproj + (size_t)r * 128 + c16 * 8;
    float4 lo = *(const float4*)(src);
    float4 hi = *(const float4*)(src + 4);
    bf16x8 pk;
    pk[0] = (short)f2bf(lo.x); pk[1] = (short)f2bf(lo.y);
    pk[2] = (short)f2bf(lo.z); pk[3] = (short)f2bf(lo.w);
    pk[4] = (short)f2bf(hi.x); pk[5] = (short)f2bf(hi.y);
    pk[6] = (short)f2bf(hi.z); pk[7] = (short)f2bf(hi.w);
    *(bf16x8*)(&Wl[r * 128 + (c16 ^ (r & 7)) * 8]) = pk;
  }
  __syncthreads();

  f32x4 acc[4][4];
#pragma unroll
  for (int mi = 0; mi < 4; ++mi)
#pragma unroll
    for (int ni = 0; ni < 4; ++ni) acc[mi][ni] = (f32x4){0.f, 0.f, 0.f, 0.f};

#pragma unroll
  for (int ks = 0; ks < 4; ++ks) {
    bf16x8 af[4], bfr[4];
    int unit = (ks * 4 + quad) ^ (m & 7);
#pragma unroll
    for (int mi = 0; mi < 4; ++mi) {
      int row = (w & 1) * 64 + mi * 16 + m;
      af[mi] = *(const bf16x8*)(&Al[row * 128 + unit * 8]);
    }
#pragma unroll
    for (int ni = 0; ni < 4; ++ni) {
      int row = (w >> 1) * 64 + ni * 16 + m;
      bfr[ni] = *(const bf16x8*)(&Wl[row * 128 + unit * 8]);
    }
#pragma unroll
    for (int mi = 0; mi < 4; ++mi)
#pragma unroll
      for (int ni = 0; ni < 4; ++ni)
        acc[mi][ni] = __builtin_amdgcn_mfma_f32_16x16x32_bf16(
            af[mi], bfr[ni], acc[mi][ni], 0, 0, 0);
  }

#pragma unroll
  for (int ni = 0; ni < 4; ++ni) {
    int n = (w >> 1) * 64 + ni * 16 + m;
    float bp = bproj[n];
#pragma unroll
    for (int mi = 0; mi < 4; ++mi) {
      int trow = tau0 + (w & 1) * 64 + mi * 16 + quad * 4;
#pragma unroll
      for (int reg = 0; reg < 4; ++reg)
        out[(size_t)(trow + reg) * 128 + n] = acc[mi][ni][reg] + bp;
    }
  }
}

extern "C" void kernel_launch(void* const* d_in, const int* in_sizes, int n_in,
                              void* d_out, int out_size, void* d_ws, size_t ws_size,
                              hipStream_t stream) {
  (void)in_sizes; (void)n_in; (void)out_size; (void)ws_size;
  const float* x     = (const float*)d_in[0];
  const float* mask  = (const float*)d_in[1];
  const float* Wqkv  = (const float*)d_in[2];
  const float* bqkv  = (const float*)d_in[3];
  const float* Wqkv2 = (const float*)d_in[4];
  const float* bqkv2 = (const float*)d_in[5];
  const float* Wp1   = (const float*)d_in[6];
  const float* bp1   = (const float*)d_in[7];
  const float* Wp2   = (const float*)d_in[8];
  const float* bp2   = (const float*)d_in[9];
  const float* lq1   = (const float*)d_in[10];
  const float* lk1   = (const float*)d_in[11];
  const float* lq2   = (const float*)d_in[12];
  const float* lk2   = (const float*)d_in[13];
  const float* subln = (const float*)d_in[14];
  const float* Wproj = (const float*)d_in[15];
  const float* bproj = (const float*)d_in[16];
  float* out = (float*)d_out;

  float* pb = (float*)d_ws;                                               // 64 KB
  unsigned short* qkvws = (unsigned short*)((char*)d_ws + 65536);         // 251,658,240 B
  unsigned short* obuf  = (unsigned short*)((char*)d_ws + 65536 + 251658240); // 50,331,648 B

  hipLaunchKernelGGL(pb_kernel, dim3(16), dim3(256), 0, stream, Wp1, bp1, Wp2, bp2, pb);
  hipLaunchKernelGGL(qkv_proj, dim3(1536), dim3(256), 0, stream,
                     x, Wqkv, bqkv, Wqkv2, bqkv2, qkvws);
  hipLaunchKernelGGL(attn_core, dim3(3072), dim3(256), 0, stream,
                     qkvws, mask, pb, lq1, lk1, lq2, lk2, subln, obuf);
  hipLaunchKernelGGL(out_proj, dim3(1536), dim3(256), 0, stream,
                     obuf, Wproj, bproj, out);
}

// Round 4
// 324.305 us; speedup vs baseline: 1.3479x; 1.3479x over previous
//
#include <hip/hip_runtime.h>
#include <math.h>

typedef __attribute__((ext_vector_type(8))) short bf16x8;
typedef __attribute__((ext_vector_type(4))) float f32x4;

#define NWMASK 192
#define SCALE_Q 0.17677669529663687f

__device__ __forceinline__ unsigned short f2bf(float f) {
  union { float f; unsigned u; } v; v.f = f;
  return (unsigned short)((v.u + 0x7fffu + ((v.u >> 16) & 1u)) >> 16);
}

__device__ __forceinline__ bf16x8 pack8(const float* src) {
  float4 lo = *(const float4*)(src);
  float4 hi = *(const float4*)(src + 4);
  bf16x8 pk;
  pk[0] = (short)f2bf(lo.x); pk[1] = (short)f2bf(lo.y);
  pk[2] = (short)f2bf(lo.z); pk[3] = (short)f2bf(lo.w);
  pk[4] = (short)f2bf(hi.x); pk[5] = (short)f2bf(hi.y);
  pk[6] = (short)f2bf(hi.z); pk[7] = (short)f2bf(hi.w);
  return pk;
}

// ---- pre-pack W~ = [Wqkv(384) ; Wqkv2(256) ; Wproj(128)] rows x 128 into
// bf16 B-fragment order: Wb[ft][ks][quad][l15][8], ft = row/16, k = ks*32+quad*8+j
__global__ void wpack_kernel(const float* __restrict__ Wqkv, const float* __restrict__ Wqkv2,
                             const float* __restrict__ Wproj, unsigned short* __restrict__ Wb) {
  int gid = blockIdx.x * 256 + threadIdx.x;       // 12288 fragment groups
  if (gid >= 12288) return;
  int l15 = gid & 15, quad = (gid >> 4) & 3, ks = (gid >> 6) & 3, ft = gid >> 8;
  int row = ft * 16 + l15;
  const float* src = (row < 384) ? (Wqkv + (size_t)row * 128)
                   : (row < 640) ? (Wqkv2 + (size_t)(row - 384) * 128)
                                 : (Wproj + (size_t)(row - 640) * 128);
  *(bf16x8*)(Wb + (size_t)gid * 8) = pack8(src + ks * 32 + quad * 8);
}

// ---- polar position bias, stored TRANSPOSED: pbT[h][col][row] ----
__global__ void pbt_kernel(const float* __restrict__ Wp1, const float* __restrict__ bp1,
                           const float* __restrict__ Wp2, const float* __restrict__ bp2,
                           float* __restrict__ pbT) {
  int idx = blockIdx.x * 256 + threadIdx.x;       // (i,j), 4096 total
  if (idx >= 4096) return;
  int i = idx >> 6, j = idx & 63;
  float dx = (float)((i & 7) - (j & 7));
  float dy = -(float)((i >> 3) - (j >> 3));
  float r = sqrtf(dx*dx + dy*dy + 1e-9f);
  float theta = atan2f(dx, dy);
  float p0 = r * (1.0f / 9.899494936611665f);
  float p1 = (theta + 3.14159265358979323846f) * (1.0f / 6.283185307179586f);
  float a0 = 0.f, a1 = 0.f, a2 = 0.f, a3 = 0.f;
  for (int f = 0; f < 64; ++f) {
    float hpre = p0 * Wp1[2*f] + p1 * Wp1[2*f+1] + bp1[f];
    float g = 0.5f * hpre * (1.0f + erff(hpre * 0.70710678118654752f));
    a0 += Wp2[f]       * g;
    a1 += Wp2[64 + f]  * g;
    a2 += Wp2[128 + f] * g;
    a3 += Wp2[192 + f] * g;
  }
  int o = j * 64 + i;                             // transposed
  pbT[o]          = a0 + bp2[0];
  pbT[4096 + o]   = a1 + bp2[1];
  pbT[8192 + o]   = a2 + bp2[2];
  pbT[12288 + o]  = a3 + bp2[3];
}

// ---- mask transposed: maskT[wm][col][row] ----
__global__ void maskt_kernel(const float* __restrict__ mask, float* __restrict__ maskT) {
  int gid = blockIdx.x * 256 + threadIdx.x;       // 786432 total
  if (gid >= 786432) return;
  int wm = gid >> 12, rc = gid & 4095, c = rc >> 6, r = rc & 63;
  maskT[gid] = mask[(size_t)wm * 4096 + r * 64 + c];
}

// ---- fully fused: one block = one window, wave w = head w ----
// LDS (u16 elems, 64 KB total):
//   XB   [0, 8192)            : x bf16 [64][128], unit^=(row&7)
//   SW_w [8192 + w*6144, +6144): per-wave scratch:
//        QBUF [0,2048) KBUF [2048,4096)  (32-elem rows, unit(0..3)^=(row&3))
//        P    [0,4096)  [64][64], unit(0..7)^=(row&7)   (overlays QBUF+KBUF)
//        VT   [4096,6144) [32 d][64 tok], unit^=(d&7)
//   OBUF [8192, 16384) : O bf16 [64][128], unit^=(row&7)  (after barrier, overlays scratch)
__global__ __launch_bounds__(256, 2)
void fused_win(const float* __restrict__ x, const unsigned short* __restrict__ Wb,
               const float* __restrict__ bqkv, const float* __restrict__ bqkv2,
               const float* __restrict__ lq1, const float* __restrict__ lk1,
               const float* __restrict__ lq2, const float* __restrict__ lk2,
               const float* __restrict__ subln, const float* __restrict__ bproj,
               const float* __restrict__ pbT, const float* __restrict__ maskT,
               float* __restrict__ out) {
  __shared__ unsigned short smem[32768];

  const int b = blockIdx.x;
  const int t = threadIdx.x;
  const int w = t >> 6;            // wave == head
  const int lane = t & 63;
  const int l15 = lane & 15;
  const int quad = lane >> 4;
  const int h = w;
  const f32x4 zero4 = (f32x4){0.f, 0.f, 0.f, 0.f};

  // ---- stage x -> XB (bf16, swizzled) ----
  {
    const float* xg = x + (size_t)b * 8192;
#pragma unroll
    for (int u = 0; u < 4; ++u) {
      int id = u * 256 + t;
      int r = id >> 4, c16 = id & 15;
      *(bf16x8*)(&smem[r * 128 + ((c16 ^ (r & 7)) * 8)]) = pack8(xg + r * 128 + c16 * 8);
    }
  }
  __syncthreads();

  float lam;
  {
    float s1 = 0.f, s2 = 0.f;
#pragma unroll
    for (int i = 0; i < 16; ++i) { s1 += lq1[i]*lk1[i]; s2 += lq2[i]*lk2[i]; }
    lam = expf(s1) - expf(s2) + 0.2f;
  }

  unsigned short* SW = smem + 8192 + w * 6144;

  // fragment-load helpers
  auto ldXB = [&](int mi, int ks) -> bf16x8 {
    int row = mi * 16 + l15;
    return *(const bf16x8*)(&smem[row * 128 + (((ks * 4 + quad) ^ (l15 & 7)) * 8)]);
  };
  auto ldWbF = [&](int ft, int ks) -> bf16x8 {
    return *(const bf16x8*)(Wb + ((((size_t)ft * 4 + ks) * 4 + quad) * 16 + l15) * 8);
  };

  // ---- generic 4-N-tile projection into acc[4][4] ----
  auto proj4 = [&](int ft0, int ft1, int ft2, int ft3, f32x4 acc[4][4]) {
#pragma unroll
    for (int mi = 0; mi < 4; ++mi)
#pragma unroll
      for (int nj = 0; nj < 4; ++nj) acc[mi][nj] = zero4;
#pragma unroll
    for (int ks = 0; ks < 4; ++ks) {
      bf16x8 xa[4], wf[4];
#pragma unroll
      for (int mi = 0; mi < 4; ++mi) xa[mi] = ldXB(mi, ks);
      wf[0] = ldWbF(ft0, ks); wf[1] = ldWbF(ft1, ks);
      wf[2] = ldWbF(ft2, ks); wf[3] = ldWbF(ft3, ks);
#pragma unroll
      for (int mi = 0; mi < 4; ++mi)
#pragma unroll
        for (int nj = 0; nj < 4; ++nj)
          acc[mi][nj] = __builtin_amdgcn_mfma_f32_16x16x32_bf16(xa[mi], wf[nj], acc[mi][nj], 0, 0, 0);
    }
  };
  // store acc (2 mats x 2 tiles) into QBUF/KBUF with bias, first mat scaled
  auto storeQK = [&](f32x4 acc[4][4], const float* biasA, const float* biasB, float scA) {
#pragma unroll
    for (int nj = 0; nj < 4; ++nj) {
      int c32 = (nj & 1) * 16 + l15;
      float bias = (nj < 2) ? biasA[c32] : biasB[c32];
      float sc = (nj < 2) ? scA : 1.0f;
      unsigned short* buf = SW + ((nj < 2) ? 0 : 2048);
#pragma unroll
      for (int mi = 0; mi < 4; ++mi)
#pragma unroll
        for (int reg = 0; reg < 4; ++reg) {
          int row = mi * 16 + quad * 4 + reg;
          buf[row * 32 + (((c32 >> 3) ^ (row & 3)) * 8) + (c32 & 7)] =
              f2bf((acc[mi][nj][reg] + bias) * sc);
        }
    }
  };
  auto qkTiles = [&](f32x4 S[4][4], bool withBias) {
    bf16x8 qa[4], kb[4];
#pragma unroll
    for (int mi = 0; mi < 4; ++mi) {
      int row = mi * 16 + l15;
      qa[mi] = *(const bf16x8*)(&SW[row * 32 + ((quad ^ (l15 & 3)) * 8)]);
      kb[mi] = *(const bf16x8*)(&SW[2048 + row * 32 + ((quad ^ (l15 & 3)) * 8)]);
    }
    const float* pbh = pbT + h * 4096;
    const float* mkh = maskT + (size_t)(b % NWMASK) * 4096;
#pragma unroll
    for (int mi = 0; mi < 4; ++mi)
#pragma unroll
      for (int ni = 0; ni < 4; ++ni) {
        f32x4 c;
        if (withBias) {
          int off = (ni * 16 + l15) * 64 + mi * 16 + quad * 4;
          float4 p4 = *(const float4*)(pbh + off);
          float4 m4 = *(const float4*)(mkh + off);
          c[0] = p4.x + m4.x; c[1] = p4.y + m4.y;
          c[2] = p4.z + m4.z; c[3] = p4.w + m4.w;
        } else c = zero4;
        S[mi][ni] = __builtin_amdgcn_mfma_f32_16x16x32_bf16(qa[mi], kb[ni], c, 0, 0, 0);
      }
  };

  // ===== q2,k2 -> S2 =====
  f32x4 S2[4][4];
  {
    f32x4 acc[4][4];
    proj4(24 + 2*h, 25 + 2*h, 32 + 2*h, 33 + 2*h, acc);            // q2 | k2 ftiles
    storeQK(acc, bqkv2 + h*32, bqkv2 + 128 + h*32, SCALE_Q);
    qkTiles(S2, false);
  }
  // ===== q,k -> S = QK + pb + mask - lam*S2 =====
  f32x4 S[4][4];
  {
    f32x4 acc[4][4];
    proj4(2*h, 1 + 2*h, 8 + 2*h, 9 + 2*h, acc);                    // q | k ftiles
    storeQK(acc, bqkv + h*32, bqkv + 128 + h*32, SCALE_Q);
    qkTiles(S, true);
#pragma unroll
    for (int mi = 0; mi < 4; ++mi)
#pragma unroll
      for (int ni = 0; ni < 4; ++ni)
#pragma unroll
        for (int reg = 0; reg < 4; ++reg)
          S[mi][ni][reg] -= lam * S2[mi][ni][reg];
  }

  // ===== softmax -> P (bf16) into SW[0..4096) =====
#pragma unroll
  for (int mi = 0; mi < 4; ++mi) {
#pragma unroll
    for (int reg = 0; reg < 4; ++reg) {
      float mx = fmaxf(fmaxf(S[mi][0][reg], S[mi][1][reg]),
                       fmaxf(S[mi][2][reg], S[mi][3][reg]));
      mx = fmaxf(mx, __shfl_xor(mx, 1));
      mx = fmaxf(mx, __shfl_xor(mx, 2));
      mx = fmaxf(mx, __shfl_xor(mx, 4));
      mx = fmaxf(mx, __shfl_xor(mx, 8));
      float e0 = __expf(S[mi][0][reg] - mx);
      float e1 = __expf(S[mi][1][reg] - mx);
      float e2 = __expf(S[mi][2][reg] - mx);
      float e3 = __expf(S[mi][3][reg] - mx);
      float sum = e0 + e1 + e2 + e3;
      sum += __shfl_xor(sum, 1);
      sum += __shfl_xor(sum, 2);
      sum += __shfl_xor(sum, 4);
      sum += __shfl_xor(sum, 8);
      float inv = 1.0f / sum;
      int row = mi * 16 + quad * 4 + reg;
      int sw = row & 7;
      unsigned short* prow = SW + row * 64;
      prow[(((l15 >> 3) + 0) ^ sw) * 8 + (l15 & 7)] = f2bf(e0 * inv);
      prow[(((l15 >> 3) + 2) ^ sw) * 8 + (l15 & 7)] = f2bf(e1 * inv);
      prow[(((l15 >> 3) + 4) ^ sw) * 8 + (l15 & 7)] = f2bf(e2 * inv);
      prow[(((l15 >> 3) + 6) ^ sw) * 8 + (l15 & 7)] = f2bf(e3 * inv);
    }
  }

  // ===== v projection -> VT [32 d][64 tok] =====
  {
    f32x4 av[4][2];
#pragma unroll
    for (int mi = 0; mi < 4; ++mi) { av[mi][0] = zero4; av[mi][1] = zero4; }
#pragma unroll
    for (int ks = 0; ks < 4; ++ks) {
      bf16x8 xa[4];
#pragma unroll
      for (int mi = 0; mi < 4; ++mi) xa[mi] = ldXB(mi, ks);
      bf16x8 w0 = ldWbF(16 + 2*h, ks), w1 = ldWbF(17 + 2*h, ks);
#pragma unroll
      for (int mi = 0; mi < 4; ++mi) {
        av[mi][0] = __builtin_amdgcn_mfma_f32_16x16x32_bf16(xa[mi], w0, av[mi][0], 0, 0, 0);
        av[mi][1] = __builtin_amdgcn_mfma_f32_16x16x32_bf16(xa[mi], w1, av[mi][1], 0, 0, 0);
      }
    }
#pragma unroll
    for (int nd = 0; nd < 2; ++nd) {
      int d = nd * 16 + l15;
      float bias = bqkv[256 + h * 32 + d];
#pragma unroll
      for (int mi = 0; mi < 4; ++mi) {
        int tok0 = mi * 16 + quad * 4;
        ushort4 pk;
        pk.x = f2bf(av[mi][nd][0] + bias);
        pk.y = f2bf(av[mi][nd][1] + bias);
        pk.z = f2bf(av[mi][nd][2] + bias);
        pk.w = f2bf(av[mi][nd][3] + bias);
        *(ushort4*)(&SW[4096 + d * 64 + (((tok0 >> 3) ^ (d & 7)) * 8) + (tok0 & 7)]) = pk;
      }
    }
  }

  // ===== PV -> O, RMSNorm in registers =====
  float ov0[4][4], ov1[4][4];
  {
    f32x4 O[4][2];
#pragma unroll
    for (int mi = 0; mi < 4; ++mi) { O[mi][0] = zero4; O[mi][1] = zero4; }
#pragma unroll
    for (int kc = 0; kc < 2; ++kc) {
      bf16x8 pa[4], vb[2];
#pragma unroll
      for (int mi = 0; mi < 4; ++mi) {
        int row = mi * 16 + l15;
        pa[mi] = *(const bf16x8*)(&SW[row * 64 + (((kc * 4 + quad) ^ (l15 & 7)) * 8)]);
      }
#pragma unroll
      for (int nd = 0; nd < 2; ++nd) {
        int d = nd * 16 + l15;
        vb[nd] = *(const bf16x8*)(&SW[4096 + d * 64 + (((kc * 4 + quad) ^ (d & 7)) * 8)]);
      }
#pragma unroll
      for (int mi = 0; mi < 4; ++mi) {
        O[mi][0] = __builtin_amdgcn_mfma_f32_16x16x32_bf16(pa[mi], vb[0], O[mi][0], 0, 0, 0);
        O[mi][1] = __builtin_amdgcn_mfma_f32_16x16x32_bf16(pa[mi], vb[1], O[mi][1], 0, 0, 0);
      }
    }
    float sw0 = subln[l15] * 0.8f;
    float sw1 = subln[16 + l15] * 0.8f;
#pragma unroll
    for (int mi = 0; mi < 4; ++mi)
#pragma unroll
      for (int reg = 0; reg < 4; ++reg) {
        float a0 = O[mi][0][reg], a1 = O[mi][1][reg];
        float ss = a0 * a0 + a1 * a1;
        ss += __shfl_xor(ss, 1);
        ss += __shfl_xor(ss, 2);
        ss += __shfl_xor(ss, 4);
        ss += __shfl_xor(ss, 8);
        float rs = 1.0f / sqrtf(ss * (1.0f / 32.0f) + 1e-9f);
        ov0[mi][reg] = a0 * rs * sw0;
        ov1[mi][reg] = a1 * rs * sw1;
      }
  }

  __syncthreads();   // all waves done with scratch; OBUF may overlay it

  // ===== O -> OBUF [64][128] bf16 swizzled =====
  {
    int c0 = h * 32 + l15, c1 = h * 32 + 16 + l15;
#pragma unroll
    for (int mi = 0; mi < 4; ++mi)
#pragma unroll
      for (int reg = 0; reg < 4; ++reg) {
        int row = mi * 16 + quad * 4 + reg;
        unsigned short* orow = smem + 8192 + row * 128;
        orow[(((c0 >> 3) ^ (row & 7)) * 8) + (c0 & 7)] = f2bf(ov0[mi][reg]);
        orow[(((c1 >> 3) ^ (row & 7)) * 8) + (c1 & 7)] = f2bf(ov1[mi][reg]);
      }
  }
  __syncthreads();

  // ===== out-projection: wave w covers output cols [w*32, w*32+32) =====
  {
    f32x4 po[4][2];
#pragma unroll
    for (int mi = 0; mi < 4; ++mi) { po[mi][0] = zero4; po[mi][1] = zero4; }
#pragma unroll
    for (int ks = 0; ks < 4; ++ks) {
      bf16x8 oa[4];
#pragma unroll
      for (int mi = 0; mi < 4; ++mi) {
        int row = mi * 16 + l15;
        oa[mi] = *(const bf16x8*)(&smem[8192 + row * 128 + (((ks * 4 + quad) ^ (l15 & 7)) * 8)]);
      }
      bf16x8 w0 = ldWbF(40 + 2*w, ks), w1 = ldWbF(41 + 2*w, ks);
#pragma unroll
      for (int mi = 0; mi < 4; ++mi) {
        po[mi][0] = __builtin_amdgcn_mfma_f32_16x16x32_bf16(oa[mi], w0, po[mi][0], 0, 0, 0);
        po[mi][1] = __builtin_amdgcn_mfma_f32_16x16x32_bf16(oa[mi], w1, po[mi][1], 0, 0, 0);
      }
    }
    float* og = out + (size_t)b * 8192;
#pragma unroll
    for (int nt = 0; nt < 2; ++nt) {
      int col = (2 * w + nt) * 16 + l15;
      float bp = bproj[col];
#pragma unroll
      for (int mi = 0; mi < 4; ++mi)
#pragma unroll
        for (int reg = 0; reg < 4; ++reg)
          og[(size_t)(mi * 16 + quad * 4 + reg) * 128 + col] = po[mi][nt][reg] + bp;
    }
  }
}

extern "C" void kernel_launch(void* const* d_in, const int* in_sizes, int n_in,
                              void* d_out, int out_size, void* d_ws, size_t ws_size,
                              hipStream_t stream) {
  (void)in_sizes; (void)n_in; (void)out_size; (void)ws_size;
  const float* x     = (const float*)d_in[0];
  const float* mask  = (const float*)d_in[1];
  const float* Wqkv  = (const float*)d_in[2];
  const float* bqkv  = (const float*)d_in[3];
  const float* Wqkv2 = (const float*)d_in[4];
  const float* bqkv2 = (const float*)d_in[5];
  const float* Wp1   = (const float*)d_in[6];
  const float* bp1   = (const float*)d_in[7];
  const float* Wp2   = (const float*)d_in[8];
  const float* bp2   = (const float*)d_in[9];
  const float* lq1   = (const float*)d_in[10];
  const float* lk1   = (const float*)d_in[11];
  const float* lq2   = (const float*)d_in[12];
  const float* lk2   = (const float*)d_in[13];
  const float* subln = (const float*)d_in[14];
  const float* Wproj = (const float*)d_in[15];
  const float* bproj = (const float*)d_in[16];
  float* out = (float*)d_out;

  unsigned short* Wb = (unsigned short*)d_ws;                         // 196608 B
  float* pbT   = (float*)((char*)d_ws + 262144);                      // 65536 B
  float* maskT = (float*)((char*)d_ws + 327680);                      // 3145728 B

  hipLaunchKernelGGL(wpack_kernel, dim3(48), dim3(256), 0, stream, Wqkv, Wqkv2, Wproj, Wb);
  hipLaunchKernelGGL(pbt_kernel, dim3(16), dim3(256), 0, stream, Wp1, bp1, Wp2, bp2, pbT);
  hipLaunchKernelGGL(maskt_kernel, dim3(3072), dim3(256), 0, stream, mask, maskT);
  hipLaunchKernelGGL(fused_win, dim3(3072), dim3(256), 0, stream,
                     x, Wb, bqkv, bqkv2, lq1, lk1, lq2, lk2, subln, bproj,
                     pbT, maskT, out);
}

// Round 5
// 312.776 us; speedup vs baseline: 1.3976x; 1.0369x over previous
//
#include <hip/hip_runtime.h>
#include <math.h>

typedef __attribute__((ext_vector_type(8))) short bf16x8;
typedef __attribute__((ext_vector_type(4))) float f32x4;

#define NWMASK 192
#define SCALE_Q 0.17677669529663687f

__device__ __forceinline__ unsigned short f2bf(float f) {
  union { float f; unsigned u; } v; v.f = f;
  return (unsigned short)((v.u + 0x7fffu + ((v.u >> 16) & 1u)) >> 16);
}

// packed f32x2 -> bf16x2 (low = a, high = b); HW instr on gfx950
__device__ __forceinline__ unsigned pkbf(float a, float b) {
#if defined(__has_builtin)
#if __has_builtin(__builtin_amdgcn_cvt_pk_bf16_f32)
  auto r = __builtin_amdgcn_cvt_pk_bf16_f32(a, b);
  union { decltype(r) v; unsigned u; } c; c.v = r; return c.u;
#else
  return (unsigned)f2bf(a) | ((unsigned)f2bf(b) << 16);
#endif
#else
  return (unsigned)f2bf(a) | ((unsigned)f2bf(b) << 16);
#endif
}

__device__ __forceinline__ void pack8s(unsigned short* dst, const float* src) {
  float4 lo = *(const float4*)(src);
  float4 hi = *(const float4*)(src + 4);
  uint4 pk;
  pk.x = pkbf(lo.x, lo.y); pk.y = pkbf(lo.z, lo.w);
  pk.z = pkbf(hi.x, hi.y); pk.w = pkbf(hi.z, hi.w);
  *(uint4*)dst = pk;
}

// ---- pre-pack W~ = [Wqkv(384) ; Wqkv2(256) ; Wproj(128)] rows x 128 into
// bf16 B-fragment order: Wb[ft][ks][quad][l15][8], ft = row/16, k = ks*32+quad*8+j
__global__ void wpack_kernel(const float* __restrict__ Wqkv, const float* __restrict__ Wqkv2,
                             const float* __restrict__ Wproj, unsigned short* __restrict__ Wb) {
  int gid = blockIdx.x * 256 + threadIdx.x;       // 12288 fragment groups
  if (gid >= 12288) return;
  int l15 = gid & 15, quad = (gid >> 4) & 3, ks = (gid >> 6) & 3, ft = gid >> 8;
  int row = ft * 16 + l15;
  const float* src = (row < 384) ? (Wqkv + (size_t)row * 128)
                   : (row < 640) ? (Wqkv2 + (size_t)(row - 384) * 128)
                                 : (Wproj + (size_t)(row - 640) * 128);
  pack8s(Wb + (size_t)gid * 8, src + ks * 32 + quad * 8);
}

// ---- polar position bias, stored TRANSPOSED: pbT[h][col][row] ----
__global__ void pbt_kernel(const float* __restrict__ Wp1, const float* __restrict__ bp1,
                           const float* __restrict__ Wp2, const float* __restrict__ bp2,
                           float* __restrict__ pbT) {
  int idx = blockIdx.x * 256 + threadIdx.x;       // (i,j), 4096 total
  if (idx >= 4096) return;
  int i = idx >> 6, j = idx & 63;
  float dx = (float)((i & 7) - (j & 7));
  float dy = -(float)((i >> 3) - (j >> 3));
  float r = sqrtf(dx*dx + dy*dy + 1e-9f);
  float theta = atan2f(dx, dy);
  float p0 = r * (1.0f / 9.899494936611665f);
  float p1 = (theta + 3.14159265358979323846f) * (1.0f / 6.283185307179586f);
  float a0 = 0.f, a1 = 0.f, a2 = 0.f, a3 = 0.f;
  for (int f = 0; f < 64; ++f) {
    float hpre = p0 * Wp1[2*f] + p1 * Wp1[2*f+1] + bp1[f];
    float g = 0.5f * hpre * (1.0f + erff(hpre * 0.70710678118654752f));
    a0 += Wp2[f]       * g;
    a1 += Wp2[64 + f]  * g;
    a2 += Wp2[128 + f] * g;
    a3 += Wp2[192 + f] * g;
  }
  int o = j * 64 + i;                             // transposed
  pbT[o]          = a0 + bp2[0];
  pbT[4096 + o]   = a1 + bp2[1];
  pbT[8192 + o]   = a2 + bp2[2];
  pbT[12288 + o]  = a3 + bp2[3];
}

// ---- mask transposed: maskT[wm][col][row] ----
__global__ void maskt_kernel(const float* __restrict__ mask, float* __restrict__ maskT) {
  int gid = blockIdx.x * 256 + threadIdx.x;       // 786432 total
  if (gid >= 786432) return;
  int wm = gid >> 12, rc = gid & 4095, c = rc >> 6, r = rc & 63;
  maskT[gid] = mask[(size_t)wm * 4096 + r * 64 + c];
}

// ---- fully fused: one block = one window, wave w = head w ----
// LDS (u16 elems, 48 KB total = 24576 u16):
//   XB   [0, 8192)             : x bf16 [64][128], unit^=(row&7)
//        after B2, wave w's VT = [w*2048, +2048): [32 d][64 tok], unit^=(d&7)
//   PW_w [8192 + w*4096, +4096): QBUF [0,2048) KBUF [2048,4096) (32-col rows, unit^=(row&3))
//        later P [0,4096) [64][64], unit^=(row&7)
//   OBUF (after B3) [8192, 16384): O bf16 [64][128], unit^=(row&7) (overlays PW_0,PW_1)
__global__ __launch_bounds__(256, 3)
void fused_win(const float* __restrict__ x, const unsigned short* __restrict__ Wb,
               const float* __restrict__ bqkv, const float* __restrict__ bqkv2,
               const float* __restrict__ lq1, const float* __restrict__ lk1,
               const float* __restrict__ lq2, const float* __restrict__ lk2,
               const float* __restrict__ subln, const float* __restrict__ bproj,
               const float* __restrict__ pbT, const float* __restrict__ maskT,
               float* __restrict__ out) {
  __shared__ unsigned short smem[24576];

  const int b = blockIdx.x;
  const int t = threadIdx.x;
  const int w = t >> 6;            // wave == head
  const int lane = t & 63;
  const int l15 = lane & 15;
  const int quad = lane >> 4;
  const int h = w;
  const f32x4 zero4 = (f32x4){0.f, 0.f, 0.f, 0.f};

  // ---- stage x -> XB (bf16, swizzled) ----
  {
    const float* xg = x + (size_t)b * 8192;
#pragma unroll
    for (int u = 0; u < 4; ++u) {
      int id = u * 256 + t;
      int r = id >> 4, c16 = id & 15;
      pack8s(&smem[r * 128 + ((c16 ^ (r & 7)) * 8)], xg + r * 128 + c16 * 8);
    }
  }
  __syncthreads();                                   // B1

  float lam;
  {
    float s1 = 0.f, s2 = 0.f;
#pragma unroll
    for (int i = 0; i < 16; ++i) { s1 += lq1[i]*lk1[i]; s2 += lq2[i]*lk2[i]; }
    lam = expf(s1) - expf(s2) + 0.2f;
  }

  unsigned short* PW = smem + 8192 + w * 4096;

  auto ldXB = [&](int mi, int ks) -> bf16x8 {
    int row = mi * 16 + l15;
    return *(const bf16x8*)(&smem[row * 128 + (((ks * 4 + quad) ^ (l15 & 7)) * 8)]);
  };
  auto ldWbF = [&](int ft, int ks) -> bf16x8 {
    return *(const bf16x8*)(Wb + ((((size_t)ft * 4 + ks) * 4 + quad) * 16 + l15) * 8);
  };

  auto proj4 = [&](int ft0, int ft1, int ft2, int ft3, f32x4 acc[4][4]) {
#pragma unroll
    for (int mi = 0; mi < 4; ++mi)
#pragma unroll
      for (int nj = 0; nj < 4; ++nj) acc[mi][nj] = zero4;
#pragma unroll
    for (int ks = 0; ks < 4; ++ks) {
      bf16x8 xa[4], wf[4];
#pragma unroll
      for (int mi = 0; mi < 4; ++mi) xa[mi] = ldXB(mi, ks);
      wf[0] = ldWbF(ft0, ks); wf[1] = ldWbF(ft1, ks);
      wf[2] = ldWbF(ft2, ks); wf[3] = ldWbF(ft3, ks);
#pragma unroll
      for (int mi = 0; mi < 4; ++mi)
#pragma unroll
        for (int nj = 0; nj < 4; ++nj)
          acc[mi][nj] = __builtin_amdgcn_mfma_f32_16x16x32_bf16(xa[mi], wf[nj], acc[mi][nj], 0, 0, 0);
    }
  };
  auto storeQK = [&](f32x4 acc[4][4], const float* biasA, const float* biasB, float scA) {
#pragma unroll
    for (int nj = 0; nj < 4; ++nj) {
      int c32 = (nj & 1) * 16 + l15;
      float bias = (nj < 2) ? biasA[c32] : biasB[c32];
      float sc = (nj < 2) ? scA : 1.0f;
      unsigned short* buf = PW + ((nj < 2) ? 0 : 2048);
#pragma unroll
      for (int mi = 0; mi < 4; ++mi) {
        unsigned p01 = pkbf((acc[mi][nj][0] + bias) * sc, (acc[mi][nj][1] + bias) * sc);
        unsigned p23 = pkbf((acc[mi][nj][2] + bias) * sc, (acc[mi][nj][3] + bias) * sc);
        int r0 = mi * 16 + quad * 4;
        buf[(r0+0) * 32 + (((c32 >> 3) ^ ((r0+0) & 3)) * 8) + (c32 & 7)] = (unsigned short)p01;
        buf[(r0+1) * 32 + (((c32 >> 3) ^ ((r0+1) & 3)) * 8) + (c32 & 7)] = (unsigned short)(p01 >> 16);
        buf[(r0+2) * 32 + (((c32 >> 3) ^ ((r0+2) & 3)) * 8) + (c32 & 7)] = (unsigned short)p23;
        buf[(r0+3) * 32 + (((c32 >> 3) ^ ((r0+3) & 3)) * 8) + (c32 & 7)] = (unsigned short)(p23 >> 16);
      }
    }
  };
  auto qkTiles = [&](f32x4 S[4][4], bool withBias) {
    bf16x8 qa[4], kb[4];
#pragma unroll
    for (int mi = 0; mi < 4; ++mi) {
      int row = mi * 16 + l15;
      qa[mi] = *(const bf16x8*)(&PW[row * 32 + ((quad ^ (l15 & 3)) * 8)]);
      kb[mi] = *(const bf16x8*)(&PW[2048 + row * 32 + ((quad ^ (l15 & 3)) * 8)]);
    }
    const float* pbh = pbT + h * 4096;
    const float* mkh = maskT + (size_t)(b % NWMASK) * 4096;
#pragma unroll
    for (int mi = 0; mi < 4; ++mi)
#pragma unroll
      for (int ni = 0; ni < 4; ++ni) {
        f32x4 c;
        if (withBias) {
          int off = (ni * 16 + l15) * 64 + mi * 16 + quad * 4;
          float4 p4 = *(const float4*)(pbh + off);
          float4 m4 = *(const float4*)(mkh + off);
          c[0] = p4.x + m4.x; c[1] = p4.y + m4.y;
          c[2] = p4.z + m4.z; c[3] = p4.w + m4.w;
        } else c = zero4;
        S[mi][ni] = __builtin_amdgcn_mfma_f32_16x16x32_bf16(qa[mi], kb[ni], c, 0, 0, 0);
      }
  };

  // ===== q2,k2 -> S2 =====
  f32x4 S2[4][4];
  {
    f32x4 acc[4][4];
    proj4(24 + 2*h, 25 + 2*h, 32 + 2*h, 33 + 2*h, acc);
    storeQK(acc, bqkv2 + h*32, bqkv2 + 128 + h*32, SCALE_Q);
    qkTiles(S2, false);
  }
  // ===== q,k -> S = QK + pb + mask - lam*S2 =====
  f32x4 S[4][4];
  {
    f32x4 acc[4][4];
    proj4(2*h, 1 + 2*h, 8 + 2*h, 9 + 2*h, acc);
    storeQK(acc, bqkv + h*32, bqkv + 128 + h*32, SCALE_Q);
    qkTiles(S, true);
#pragma unroll
    for (int mi = 0; mi < 4; ++mi)
#pragma unroll
      for (int ni = 0; ni < 4; ++ni)
#pragma unroll
        for (int reg = 0; reg < 4; ++reg)
          S[mi][ni][reg] -= lam * S2[mi][ni][reg];
  }

  // ===== softmax -> P (bf16) into PW[0..4096) (QBUF/KBUF dead) =====
#pragma unroll
  for (int mi = 0; mi < 4; ++mi) {
#pragma unroll
    for (int reg = 0; reg < 4; ++reg) {
      float mx = fmaxf(fmaxf(S[mi][0][reg], S[mi][1][reg]),
                       fmaxf(S[mi][2][reg], S[mi][3][reg]));
      mx = fmaxf(mx, __shfl_xor(mx, 1));
      mx = fmaxf(mx, __shfl_xor(mx, 2));
      mx = fmaxf(mx, __shfl_xor(mx, 4));
      mx = fmaxf(mx, __shfl_xor(mx, 8));
      float e0 = __expf(S[mi][0][reg] - mx);
      float e1 = __expf(S[mi][1][reg] - mx);
      float e2 = __expf(S[mi][2][reg] - mx);
      float e3 = __expf(S[mi][3][reg] - mx);
      float sum = e0 + e1 + e2 + e3;
      sum += __shfl_xor(sum, 1);
      sum += __shfl_xor(sum, 2);
      sum += __shfl_xor(sum, 4);
      sum += __shfl_xor(sum, 8);
      float inv = 1.0f / sum;
      int row = mi * 16 + quad * 4 + reg;
      int sw = row & 7;
      unsigned short* prow = PW + row * 64;
      unsigned p01 = pkbf(e0 * inv, e1 * inv);
      unsigned p23 = pkbf(e2 * inv, e3 * inv);
      prow[(((l15 >> 3) + 0) ^ sw) * 8 + (l15 & 7)] = (unsigned short)p01;
      prow[(((l15 >> 3) + 2) ^ sw) * 8 + (l15 & 7)] = (unsigned short)(p01 >> 16);
      prow[(((l15 >> 3) + 4) ^ sw) * 8 + (l15 & 7)] = (unsigned short)p23;
      prow[(((l15 >> 3) + 6) ^ sw) * 8 + (l15 & 7)] = (unsigned short)(p23 >> 16);
    }
  }

  // ===== v projection (last XB reads) =====
  f32x4 av[4][2];
  {
#pragma unroll
    for (int mi = 0; mi < 4; ++mi) { av[mi][0] = zero4; av[mi][1] = zero4; }
#pragma unroll
    for (int ks = 0; ks < 4; ++ks) {
      bf16x8 xa[4];
#pragma unroll
      for (int mi = 0; mi < 4; ++mi) xa[mi] = ldXB(mi, ks);
      bf16x8 w0 = ldWbF(16 + 2*h, ks), w1 = ldWbF(17 + 2*h, ks);
#pragma unroll
      for (int mi = 0; mi < 4; ++mi) {
        av[mi][0] = __builtin_amdgcn_mfma_f32_16x16x32_bf16(xa[mi], w0, av[mi][0], 0, 0, 0);
        av[mi][1] = __builtin_amdgcn_mfma_f32_16x16x32_bf16(xa[mi], w1, av[mi][1], 0, 0, 0);
      }
    }
  }
  __syncthreads();                                   // B2: XB reads done everywhere

  // ===== VT [32 d][64 tok] into XB region (wave w's 4 KB slice) =====
  {
    unsigned short* VT = smem + w * 2048;
#pragma unroll
    for (int nd = 0; nd < 2; ++nd) {
      int d = nd * 16 + l15;
      float bias = bqkv[256 + h * 32 + d];
#pragma unroll
      for (int mi = 0; mi < 4; ++mi) {
        int tok0 = mi * 16 + quad * 4;
        uint2 pk;
        pk.x = pkbf(av[mi][nd][0] + bias, av[mi][nd][1] + bias);
        pk.y = pkbf(av[mi][nd][2] + bias, av[mi][nd][3] + bias);
        *(uint2*)(&VT[d * 64 + (((tok0 >> 3) ^ (d & 7)) * 8) + (tok0 & 7)]) = pk;
      }
    }
  }

  // ===== PV -> O, RMSNorm in registers =====
  float ov0[4][4], ov1[4][4];
  {
    unsigned short* VT = smem + w * 2048;
    f32x4 O[4][2];
#pragma unroll
    for (int mi = 0; mi < 4; ++mi) { O[mi][0] = zero4; O[mi][1] = zero4; }
#pragma unroll
    for (int kc = 0; kc < 2; ++kc) {
      bf16x8 pa[4], vb[2];
#pragma unroll
      for (int mi = 0; mi < 4; ++mi) {
        int row = mi * 16 + l15;
        pa[mi] = *(const bf16x8*)(&PW[row * 64 + (((kc * 4 + quad) ^ (row & 7)) * 8)]);
      }
#pragma unroll
      for (int nd = 0; nd < 2; ++nd) {
        int d = nd * 16 + l15;
        vb[nd] = *(const bf16x8*)(&VT[d * 64 + (((kc * 4 + quad) ^ (d & 7)) * 8)]);
      }
#pragma unroll
      for (int mi = 0; mi < 4; ++mi) {
        O[mi][0] = __builtin_amdgcn_mfma_f32_16x16x32_bf16(pa[mi], vb[0], O[mi][0], 0, 0, 0);
        O[mi][1] = __builtin_amdgcn_mfma_f32_16x16x32_bf16(pa[mi], vb[1], O[mi][1], 0, 0, 0);
      }
    }
    float sw0 = subln[l15] * 0.8f;
    float sw1 = subln[16 + l15] * 0.8f;
#pragma unroll
    for (int mi = 0; mi < 4; ++mi)
#pragma unroll
      for (int reg = 0; reg < 4; ++reg) {
        float a0 = O[mi][0][reg], a1 = O[mi][1][reg];
        float ss = a0 * a0 + a1 * a1;
        ss += __shfl_xor(ss, 1);
        ss += __shfl_xor(ss, 2);
        ss += __shfl_xor(ss, 4);
        ss += __shfl_xor(ss, 8);
        float rs = 1.0f / sqrtf(ss * (1.0f / 32.0f) + 1e-9f);
        ov0[mi][reg] = a0 * rs * sw0;
        ov1[mi][reg] = a1 * rs * sw1;
      }
  }

  __syncthreads();                                   // B3: P/VT reads done; OBUF may overlay

  // ===== O -> OBUF [64][128] bf16 swizzled =====
  {
    int c0 = h * 32 + l15, c1 = h * 32 + 16 + l15;
#pragma unroll
    for (int mi = 0; mi < 4; ++mi)
#pragma unroll
      for (int reg = 0; reg < 4; ++reg) {
        int row = mi * 16 + quad * 4 + reg;
        unsigned short* orow = smem + 8192 + row * 128;
        unsigned p = pkbf(ov0[mi][reg], ov1[mi][reg]);
        orow[(((c0 >> 3) ^ (row & 7)) * 8) + (c0 & 7)] = (unsigned short)p;
        orow[(((c1 >> 3) ^ (row & 7)) * 8) + (c1 & 7)] = (unsigned short)(p >> 16);
      }
  }
  __syncthreads();                                   // B4

  // ===== out-projection: wave w covers output cols [w*32, w*32+32) =====
  {
    f32x4 po[4][2];
#pragma unroll
    for (int mi = 0; mi < 4; ++mi) { po[mi][0] = zero4; po[mi][1] = zero4; }
#pragma unroll
    for (int ks = 0; ks < 4; ++ks) {
      bf16x8 oa[4];
#pragma unroll
      for (int mi = 0; mi < 4; ++mi) {
        int row = mi * 16 + l15;
        oa[mi] = *(const bf16x8*)(&smem[8192 + row * 128 + (((ks * 4 + quad) ^ (l15 & 7)) * 8)]);
      }
      bf16x8 w0 = ldWbF(40 + 2*w, ks), w1 = ldWbF(41 + 2*w, ks);
#pragma unroll
      for (int mi = 0; mi < 4; ++mi) {
        po[mi][0] = __builtin_amdgcn_mfma_f32_16x16x32_bf16(oa[mi], w0, po[mi][0], 0, 0, 0);
        po[mi][1] = __builtin_amdgcn_mfma_f32_16x16x32_bf16(oa[mi], w1, po[mi][1], 0, 0, 0);
      }
    }
    float* og = out + (size_t)b * 8192;
#pragma unroll
    for (int nt = 0; nt < 2; ++nt) {
      int col = (2 * w + nt) * 16 + l15;
      float bp = bproj[col];
#pragma unroll
      for (int mi = 0; mi < 4; ++mi)
#pragma unroll
        for (int reg = 0; reg < 4; ++reg)
          og[(size_t)(mi * 16 + quad * 4 + reg) * 128 + col] = po[mi][nt][reg] + bp;
    }
  }
}

extern "C" void kernel_launch(void* const* d_in, const int* in_sizes, int n_in,
                              void* d_out, int out_size, void* d_ws, size_t ws_size,
                              hipStream_t stream) {
  (void)in_sizes; (void)n_in; (void)out_size; (void)ws_size;
  const float* x     = (const float*)d_in[0];
  const float* mask  = (const float*)d_in[1];
  const float* Wqkv  = (const float*)d_in[2];
  const float* bqkv  = (const float*)d_in[3];
  const float* Wqkv2 = (const float*)d_in[4];
  const float* bqkv2 = (const float*)d_in[5];
  const float* Wp1   = (const float*)d_in[6];
  const float* bp1   = (const float*)d_in[7];
  const float* Wp2   = (const float*)d_in[8];
  const float* bp2   = (const float*)d_in[9];
  const float* lq1   = (const float*)d_in[10];
  const float* lk1   = (const float*)d_in[11];
  const float* lq2   = (const float*)d_in[12];
  const float* lk2   = (const float*)d_in[13];
  const float* subln = (const float*)d_in[14];
  const float* Wproj = (const float*)d_in[15];
  const float* bproj = (const float*)d_in[16];
  float* out = (float*)d_out;

  unsigned short* Wb = (unsigned short*)d_ws;                         // 196608 B
  float* pbT   = (float*)((char*)d_ws + 262144);                      // 65536 B
  float* maskT = (float*)((char*)d_ws + 327680);                      // 3145728 B

  hipLaunchKernelGGL(wpack_kernel, dim3(48), dim3(256), 0, stream, Wqkv, Wqkv2, Wproj, Wb);
  hipLaunchKernelGGL(pbt_kernel, dim3(16), dim3(256), 0, stream, Wp1, bp1, Wp2, bp2, pbT);
  hipLaunchKernelGGL(maskt_kernel, dim3(3072), dim3(256), 0, stream, mask, maskT);
  hipLaunchKernelGGL(fused_win, dim3(3072), dim3(256), 0, stream,
                     x, Wb, bqkv, bqkv2, lq1, lk1, lq2, lk2, subln, bproj,
                     pbT, maskT, out);
}

// Round 6
// 311.530 us; speedup vs baseline: 1.4032x; 1.0040x over previous
//
#include <hip/hip_runtime.h>
#include <math.h>

typedef __attribute__((ext_vector_type(8))) short bf16x8;
typedef __attribute__((ext_vector_type(4))) float f32x4;

#define NWMASK 192
#define SCALE_Q 0.17677669529663687f

__device__ __forceinline__ unsigned short f2bf(float f) {
  union { float f; unsigned u; } v; v.f = f;
  return (unsigned short)((v.u + 0x7fffu + ((v.u >> 16) & 1u)) >> 16);
}

__device__ __forceinline__ unsigned pkbf(float a, float b) {
#if defined(__has_builtin)
#if __has_builtin(__builtin_amdgcn_cvt_pk_bf16_f32)
  auto r = __builtin_amdgcn_cvt_pk_bf16_f32(a, b);
  union { decltype(r) v; unsigned u; } c; c.v = r; return c.u;
#else
  return (unsigned)f2bf(a) | ((unsigned)f2bf(b) << 16);
#endif
#else
  return (unsigned)f2bf(a) | ((unsigned)f2bf(b) << 16);
#endif
}

__device__ __forceinline__ void pack8s(unsigned short* dst, const float* src) {
  float4 lo = *(const float4*)(src);
  float4 hi = *(const float4*)(src + 4);
  uint4 pk;
  pk.x = pkbf(lo.x, lo.y); pk.y = pkbf(lo.z, lo.w);
  pk.z = pkbf(hi.x, hi.y); pk.w = pkbf(hi.z, hi.w);
  *(uint4*)dst = pk;
}

// ---- single prep kernel: blocks 0-47 wpack, 48-63 pbT, 64-3135 maskT ----
__global__ void prep_kernel(const float* __restrict__ Wqkv, const float* __restrict__ Wqkv2,
                            const float* __restrict__ Wproj,
                            const float* __restrict__ Wp1, const float* __restrict__ bp1,
                            const float* __restrict__ Wp2, const float* __restrict__ bp2,
                            const float* __restrict__ mask,
                            unsigned short* __restrict__ Wb, float* __restrict__ pbT,
                            float* __restrict__ maskT) {
  int bid = blockIdx.x;
  if (bid < 48) {
    int gid = bid * 256 + threadIdx.x;            // 12288 fragment groups
    int l15 = gid & 15, quad = (gid >> 4) & 3, ks = (gid >> 6) & 3, ft = gid >> 8;
    int row = ft * 16 + l15;
    const float* src = (row < 384) ? (Wqkv + (size_t)row * 128)
                     : (row < 640) ? (Wqkv2 + (size_t)(row - 384) * 128)
                                   : (Wproj + (size_t)(row - 640) * 128);
    pack8s(Wb + (size_t)gid * 8, src + ks * 32 + quad * 8);
  } else if (bid < 64) {
    int idx = (bid - 48) * 256 + threadIdx.x;     // (i,j), 4096 total
    int i = idx >> 6, j = idx & 63;
    float dx = (float)((i & 7) - (j & 7));
    float dy = -(float)((i >> 3) - (j >> 3));
    float r = sqrtf(dx*dx + dy*dy + 1e-9f);
    float theta = atan2f(dx, dy);
    float p0 = r * (1.0f / 9.899494936611665f);
    float p1 = (theta + 3.14159265358979323846f) * (1.0f / 6.283185307179586f);
    float a0 = 0.f, a1 = 0.f, a2 = 0.f, a3 = 0.f;
    for (int f = 0; f < 64; ++f) {
      float hpre = p0 * Wp1[2*f] + p1 * Wp1[2*f+1] + bp1[f];
      float g = 0.5f * hpre * (1.0f + erff(hpre * 0.70710678118654752f));
      a0 += Wp2[f]       * g;
      a1 += Wp2[64 + f]  * g;
      a2 += Wp2[128 + f] * g;
      a3 += Wp2[192 + f] * g;
    }
    int o = j * 64 + i;                           // transposed
    pbT[o]          = a0 + bp2[0];
    pbT[4096 + o]   = a1 + bp2[1];
    pbT[8192 + o]   = a2 + bp2[2];
    pbT[12288 + o]  = a3 + bp2[3];
  } else {
    int gid = (bid - 64) * 256 + threadIdx.x;     // 786432 total
    int wm = gid >> 12, rc = gid & 4095, c = rc >> 6, r = rc & 63;
    maskT[gid] = mask[(size_t)wm * 4096 + r * 64 + c];
  }
}

// ---- fully fused: one block = one window, wave w = head w ----
// LDS (u16 elems, 48 KB):
//   XB [0,8192): x bf16 [64][128] swizzled; after B2 wave w's VT=[w*2048,+2048) [32][64]
//   PW_w [8192+w*4096,+4096): QBUF [0,2048) KBUF [2048,4096); later P [0,4096) [64][64]
//   OBUF (after B3) [8192,16384): O bf16 [64][128] (overlays PW_0, PW_1)
// NOTE: softmax is computed WITHOUT max-subtraction and WITHOUT normalization:
//   plain E=exp(s) is exact (logits bounded, exp(-inf)=0 ok), and the row-sum
//   cancels exactly in the downstream RMSNorm (scale invariance; eps is O(1e-8)).
__global__ __launch_bounds__(256, 3)
void fused_win(const float* __restrict__ x, const unsigned short* __restrict__ Wb,
               const float* __restrict__ bqkv, const float* __restrict__ bqkv2,
               const float* __restrict__ lq1, const float* __restrict__ lk1,
               const float* __restrict__ lq2, const float* __restrict__ lk2,
               const float* __restrict__ subln, const float* __restrict__ bproj,
               const float* __restrict__ pbT, const float* __restrict__ maskT,
               float* __restrict__ out) {
  __shared__ unsigned short smem[24576];

  const int b = blockIdx.x;
  const int t = threadIdx.x;
  const int w = t >> 6;            // wave == head
  const int lane = t & 63;
  const int l15 = lane & 15;
  const int quad = lane >> 4;
  const int h = w;
  const f32x4 zero4 = (f32x4){0.f, 0.f, 0.f, 0.f};

  // ---- stage x -> XB ----
  {
    const float* xg = x + (size_t)b * 8192;
#pragma unroll
    for (int u = 0; u < 4; ++u) {
      int id = u * 256 + t;
      int r = id >> 4, c16 = id & 15;
      pack8s(&smem[r * 128 + ((c16 ^ (r & 7)) * 8)], xg + r * 128 + c16 * 8);
    }
  }
  __syncthreads();                                   // B1

  float lam;
  {
    float s1 = 0.f, s2 = 0.f;
#pragma unroll
    for (int i = 0; i < 16; ++i) { s1 += lq1[i]*lk1[i]; s2 += lq2[i]*lk2[i]; }
    lam = expf(s1) - expf(s2) + 0.2f;
  }

  unsigned short* PW = smem + 8192 + w * 4096;

  auto ldXB = [&](int mi, int ks) -> bf16x8 {
    int row = mi * 16 + l15;
    return *(const bf16x8*)(&smem[row * 128 + (((ks * 4 + quad) ^ (l15 & 7)) * 8)]);
  };
  auto ldWbF = [&](int ft, int ks) -> bf16x8 {
    return *(const bf16x8*)(Wb + ((((size_t)ft * 4 + ks) * 4 + quad) * 16 + l15) * 8);
  };

  auto proj4 = [&](int ft0, int ft1, int ft2, int ft3, f32x4 acc[4][4]) {
#pragma unroll
    for (int mi = 0; mi < 4; ++mi)
#pragma unroll
      for (int nj = 0; nj < 4; ++nj) acc[mi][nj] = zero4;
#pragma unroll
    for (int ks = 0; ks < 4; ++ks) {
      bf16x8 xa[4], wf[4];
#pragma unroll
      for (int mi = 0; mi < 4; ++mi) xa[mi] = ldXB(mi, ks);
      wf[0] = ldWbF(ft0, ks); wf[1] = ldWbF(ft1, ks);
      wf[2] = ldWbF(ft2, ks); wf[3] = ldWbF(ft3, ks);
#pragma unroll
      for (int mi = 0; mi < 4; ++mi)
#pragma unroll
        for (int nj = 0; nj < 4; ++nj)
          acc[mi][nj] = __builtin_amdgcn_mfma_f32_16x16x32_bf16(xa[mi], wf[nj], acc[mi][nj], 0, 0, 0);
    }
  };
  // store 2 mats (A scaled scA, B unscaled) into QBUF/KBUF
  auto storeQK = [&](f32x4 acc[4][4], const float* biasA, const float* biasB, float scA) {
#pragma unroll
    for (int nj = 0; nj < 4; ++nj) {
      int c32 = (nj & 1) * 16 + l15;
      float bias = (nj < 2) ? biasA[c32] : biasB[c32];
      float sc = (nj < 2) ? scA : 1.0f;
      unsigned short* buf = PW + ((nj < 2) ? 0 : 2048);
#pragma unroll
      for (int mi = 0; mi < 4; ++mi) {
        unsigned p01 = pkbf((acc[mi][nj][0] + bias) * sc, (acc[mi][nj][1] + bias) * sc);
        unsigned p23 = pkbf((acc[mi][nj][2] + bias) * sc, (acc[mi][nj][3] + bias) * sc);
        int r0 = mi * 16 + quad * 4;
        buf[(r0+0) * 32 + (((c32 >> 3) ^ ((r0+0) & 3)) * 8) + (c32 & 7)] = (unsigned short)p01;
        buf[(r0+1) * 32 + (((c32 >> 3) ^ ((r0+1) & 3)) * 8) + (c32 & 7)] = (unsigned short)(p01 >> 16);
        buf[(r0+2) * 32 + (((c32 >> 3) ^ ((r0+2) & 3)) * 8) + (c32 & 7)] = (unsigned short)p23;
        buf[(r0+3) * 32 + (((c32 >> 3) ^ ((r0+3) & 3)) * 8) + (c32 & 7)] = (unsigned short)(p23 >> 16);
      }
    }
  };
  // S (in/out) += QBUF x KBUF^T, optionally seeding C from pbT+maskT
  auto qkTiles = [&](f32x4 S[4][4], bool seedBias) {
    bf16x8 qa[4], kb[4];
#pragma unroll
    for (int mi = 0; mi < 4; ++mi) {
      int row = mi * 16 + l15;
      qa[mi] = *(const bf16x8*)(&PW[row * 32 + ((quad ^ (l15 & 3)) * 8)]);
      kb[mi] = *(const bf16x8*)(&PW[2048 + row * 32 + ((quad ^ (l15 & 3)) * 8)]);
    }
    const float* pbh = pbT + h * 4096;
    const float* mkh = maskT + (size_t)(b % NWMASK) * 4096;
#pragma unroll
    for (int mi = 0; mi < 4; ++mi)
#pragma unroll
      for (int ni = 0; ni < 4; ++ni) {
        f32x4 c;
        if (seedBias) {
          int off = (ni * 16 + l15) * 64 + mi * 16 + quad * 4;
          float4 p4 = *(const float4*)(pbh + off);
          float4 m4 = *(const float4*)(mkh + off);
          c[0] = p4.x + m4.x; c[1] = p4.y + m4.y;
          c[2] = p4.z + m4.z; c[3] = p4.w + m4.w;
        } else c = S[mi][ni];
        S[mi][ni] = __builtin_amdgcn_mfma_f32_16x16x32_bf16(qa[mi], kb[ni], c, 0, 0, 0);
      }
  };

  // ===== secondary: q2' = (q2+b)*(-lam*scale), k2 -> S = q2'k2 + pb + mask =====
  f32x4 S[4][4];
  {
    f32x4 acc[4][4];
    proj4(24 + 2*h, 25 + 2*h, 32 + 2*h, 33 + 2*h, acc);
    storeQK(acc, bqkv2 + h*32, bqkv2 + 128 + h*32, -lam * SCALE_Q);
    qkTiles(S, true);
  }
  // ===== primary: q,k -> S += qk  (C-chained; no separate S2, no combine) =====
  {
    f32x4 acc[4][4];
    proj4(2*h, 1 + 2*h, 8 + 2*h, 9 + 2*h, acc);
    storeQK(acc, bqkv + h*32, bqkv + 128 + h*32, SCALE_Q);
    qkTiles(S, false);
  }

  // ===== E = exp(S) -> P (bf16, UNNORMALIZED) into PW[0,4096) =====
#pragma unroll
  for (int mi = 0; mi < 4; ++mi) {
#pragma unroll
    for (int reg = 0; reg < 4; ++reg) {
      float e0 = __expf(S[mi][0][reg]);
      float e1 = __expf(S[mi][1][reg]);
      float e2 = __expf(S[mi][2][reg]);
      float e3 = __expf(S[mi][3][reg]);
      int row = mi * 16 + quad * 4 + reg;
      int sw = row & 7;
      unsigned short* prow = PW + row * 64;
      unsigned p01 = pkbf(e0, e1);
      unsigned p23 = pkbf(e2, e3);
      prow[(((l15 >> 3) + 0) ^ sw) * 8 + (l15 & 7)] = (unsigned short)p01;
      prow[(((l15 >> 3) + 2) ^ sw) * 8 + (l15 & 7)] = (unsigned short)(p01 >> 16);
      prow[(((l15 >> 3) + 4) ^ sw) * 8 + (l15 & 7)] = (unsigned short)p23;
      prow[(((l15 >> 3) + 6) ^ sw) * 8 + (l15 & 7)] = (unsigned short)(p23 >> 16);
    }
  }

  // ===== v projection (last XB reads) =====
  f32x4 av[4][2];
  {
#pragma unroll
    for (int mi = 0; mi < 4; ++mi) { av[mi][0] = zero4; av[mi][1] = zero4; }
#pragma unroll
    for (int ks = 0; ks < 4; ++ks) {
      bf16x8 xa[4];
#pragma unroll
      for (int mi = 0; mi < 4; ++mi) xa[mi] = ldXB(mi, ks);
      bf16x8 w0 = ldWbF(16 + 2*h, ks), w1 = ldWbF(17 + 2*h, ks);
#pragma unroll
      for (int mi = 0; mi < 4; ++mi) {
        av[mi][0] = __builtin_amdgcn_mfma_f32_16x16x32_bf16(xa[mi], w0, av[mi][0], 0, 0, 0);
        av[mi][1] = __builtin_amdgcn_mfma_f32_16x16x32_bf16(xa[mi], w1, av[mi][1], 0, 0, 0);
      }
    }
  }
  __syncthreads();                                   // B2: XB reads done everywhere

  // ===== VT [32 d][64 tok] into XB region (wave w's slice) =====
  {
    unsigned short* VT = smem + w * 2048;
#pragma unroll
    for (int nd = 0; nd < 2; ++nd) {
      int d = nd * 16 + l15;
      float bias = bqkv[256 + h * 32 + d];
#pragma unroll
      for (int mi = 0; mi < 4; ++mi) {
        int tok0 = mi * 16 + quad * 4;
        uint2 pk;
        pk.x = pkbf(av[mi][nd][0] + bias, av[mi][nd][1] + bias);
        pk.y = pkbf(av[mi][nd][2] + bias, av[mi][nd][3] + bias);
        *(uint2*)(&VT[d * 64 + (((tok0 >> 3) ^ (d & 7)) * 8) + (tok0 & 7)]) = pk;
      }
    }
  }

  // ===== PV -> O (unnormalized), RMSNorm folds away the softmax sum =====
  float ov0[4][4], ov1[4][4];
  {
    unsigned short* VT = smem + w * 2048;
    f32x4 O[4][2];
#pragma unroll
    for (int mi = 0; mi < 4; ++mi) { O[mi][0] = zero4; O[mi][1] = zero4; }
#pragma unroll
    for (int kc = 0; kc < 2; ++kc) {
      bf16x8 pa[4], vb[2];
#pragma unroll
      for (int mi = 0; mi < 4; ++mi) {
        int row = mi * 16 + l15;
        pa[mi] = *(const bf16x8*)(&PW[row * 64 + (((kc * 4 + quad) ^ (row & 7)) * 8)]);
      }
#pragma unroll
      for (int nd = 0; nd < 2; ++nd) {
        int d = nd * 16 + l15;
        vb[nd] = *(const bf16x8*)(&VT[d * 64 + (((kc * 4 + quad) ^ (d & 7)) * 8)]);
      }
#pragma unroll
      for (int mi = 0; mi < 4; ++mi) {
        O[mi][0] = __builtin_amdgcn_mfma_f32_16x16x32_bf16(pa[mi], vb[0], O[mi][0], 0, 0, 0);
        O[mi][1] = __builtin_amdgcn_mfma_f32_16x16x32_bf16(pa[mi], vb[1], O[mi][1], 0, 0, 0);
      }
    }
    float sw0 = subln[l15] * 0.8f;
    float sw1 = subln[16 + l15] * 0.8f;
#pragma unroll
    for (int mi = 0; mi < 4; ++mi)
#pragma unroll
      for (int reg = 0; reg < 4; ++reg) {
        float a0 = O[mi][0][reg], a1 = O[mi][1][reg];
        float ss = a0 * a0 + a1 * a1;
        ss += __shfl_xor(ss, 1);
        ss += __shfl_xor(ss, 2);
        ss += __shfl_xor(ss, 4);
        ss += __shfl_xor(ss, 8);
        float rs = 1.0f / sqrtf(ss * (1.0f / 32.0f));   // eps*sum^2 negligible
        ov0[mi][reg] = a0 * rs * sw0;
        ov1[mi][reg] = a1 * rs * sw1;
      }
  }

  __syncthreads();                                   // B3

  // ===== O -> OBUF [64][128] =====
  {
    int c0 = h * 32 + l15, c1 = h * 32 + 16 + l15;
#pragma unroll
    for (int mi = 0; mi < 4; ++mi)
#pragma unroll
      for (int reg = 0; reg < 4; ++reg) {
        int row = mi * 16 + quad * 4 + reg;
        unsigned short* orow = smem + 8192 + row * 128;
        unsigned p = pkbf(ov0[mi][reg], ov1[mi][reg]);
        orow[(((c0 >> 3) ^ (row & 7)) * 8) + (c0 & 7)] = (unsigned short)p;
        orow[(((c1 >> 3) ^ (row & 7)) * 8) + (c1 & 7)] = (unsigned short)(p >> 16);
      }
  }
  __syncthreads();                                   // B4

  // ===== out-projection =====
  {
    f32x4 po[4][2];
#pragma unroll
    for (int mi = 0; mi < 4; ++mi) { po[mi][0] = zero4; po[mi][1] = zero4; }
#pragma unroll
    for (int ks = 0; ks < 4; ++ks) {
      bf16x8 oa[4];
#pragma unroll
      for (int mi = 0; mi < 4; ++mi) {
        int row = mi * 16 + l15;
        oa[mi] = *(const bf16x8*)(&smem[8192 + row * 128 + (((ks * 4 + quad) ^ (l15 & 7)) * 8)]);
      }
      bf16x8 w0 = ldWbF(40 + 2*w, ks), w1 = ldWbF(41 + 2*w, ks);
#pragma unroll
      for (int mi = 0; mi < 4; ++mi) {
        po[mi][0] = __builtin_amdgcn_mfma_f32_16x16x32_bf16(oa[mi], w0, po[mi][0], 0, 0, 0);
        po[mi][1] = __builtin_amdgcn_mfma_f32_16x16x32_bf16(oa[mi], w1, po[mi][1], 0, 0, 0);
      }
    }
    float* og = out + (size_t)b * 8192;
#pragma unroll
    for (int nt = 0; nt < 2; ++nt) {
      int col = (2 * w + nt) * 16 + l15;
      float bp = bproj[col];
#pragma unroll
      for (int mi = 0; mi < 4; ++mi)
#pragma unroll
        for (int reg = 0; reg < 4; ++reg)
          og[(size_t)(mi * 16 + quad * 4 + reg) * 128 + col] = po[mi][nt][reg] + bp;
    }
  }
}

extern "C" void kernel_launch(void* const* d_in, const int* in_sizes, int n_in,
                              void* d_out, int out_size, void* d_ws, size_t ws_size,
                              hipStream_t stream) {
  (void)in_sizes; (void)n_in; (void)out_size; (void)ws_size;
  const float* x     = (const float*)d_in[0];
  const float* mask  = (const float*)d_in[1];
  const float* Wqkv  = (const float*)d_in[2];
  const float* bqkv  = (const float*)d_in[3];
  const float* Wqkv2 = (const float*)d_in[4];
  const float* bqkv2 = (const float*)d_in[5];
  const float* Wp1   = (const float*)d_in[6];
  const float* bp1   = (const float*)d_in[7];
  const float* Wp2   = (const float*)d_in[8];
  const float* bp2   = (const float*)d_in[9];
  const float* lq1   = (const float*)d_in[10];
  const float* lk1   = (const float*)d_in[11];
  const float* lq2   = (const float*)d_in[12];
  const float* lk2   = (const float*)d_in[13];
  const float* subln = (const float*)d_in[14];
  const float* Wproj = (const float*)d_in[15];
  const float* bproj = (const float*)d_in[16];
  float* out = (float*)d_out;

  unsigned short* Wb = (unsigned short*)d_ws;                         // 196608 B
  float* pbT   = (float*)((char*)d_ws + 262144);                      // 65536 B
  float* maskT = (float*)((char*)d_ws + 327680);                      // 3145728 B

  hipLaunchKernelGGL(prep_kernel, dim3(3136), dim3(256), 0, stream,
                     Wqkv, Wqkv2, Wproj, Wp1, bp1, Wp2, bp2, mask, Wb, pbT, maskT);
  hipLaunchKernelGGL(fused_win, dim3(3072), dim3(256), 0, stream,
                     x, Wb, bqkv, bqkv2, lq1, lk1, lq2, lk2, subln, bproj,
                     pbT, maskT, out);
}